// Round 1
// baseline (232.002 us; speedup 1.0000x reference)
//
#include <hip/hip_runtime.h>

// SpectralMultiHeadAttention on MI355X (gfx950)
// b=4, hw=16384, c=256, heads=8, dh=32.
// Reformulation: S[b] = x^T x (256x256);  G = Wq^T S Wk;  qss = diag(Wq^T S Wq);
// kss = diag(Wk^T S Wk);  A = softmax(G_blocks / (nq nk sqrt(hw)));
// out = x @ (Wv @ Abig^T @ Wout).   q/k/v never materialized.
// R4: (a) k_sgemm exploits S = P P^T symmetry: one 256x256 tile per (b,ks)
//     block, both MFMA operands read from ONE staged LDS panel -> xT staging
//     reads drop 134 MB -> 33.6 MB. (b) k_out widened to BN=256 so xb is
//     staged once (67 -> 33.6 MB). (c) middle fp32 GEMMs use [k][m] LDS
//     layout + float4 reads (2 ds_read_b128 per k instead of 8 ds_read_b32).

#define B_   4
#define HW_  16384
#define C_   256

typedef __attribute__((ext_vector_type(8))) short short8;
typedef __attribute__((ext_vector_type(4))) float floatx4;

__device__ __forceinline__ unsigned short f2bf(float f) {
  unsigned u = __builtin_bit_cast(unsigned, f);
  u += 0x7FFFu + ((u >> 16) & 1u);          // round-to-nearest-even
  return (unsigned short)(u >> 16);
}

__device__ __forceinline__ void gl_lds16(const unsigned short* g, unsigned short* l) {
  __builtin_amdgcn_global_load_lds(
      (const __attribute__((address_space(1))) unsigned int*)g,
      (__attribute__((address_space(3))) unsigned int*)l, 16, 0, 0);
}

// ---------------------------------------------------------------------------
// K1: cast fp32 -> bf16, emit xb (row-major [b*hw][c]) and xT ([b][c][hw]).
// grid 4096 = b(4) * ptile(256) * ctile(4), 256 thr. 64x64 tiles via LDS.
// ---------------------------------------------------------------------------
__global__ __launch_bounds__(256) void k_cast_tr(const float* __restrict__ x,
                                                 unsigned short* __restrict__ xb,
                                                 unsigned short* __restrict__ xT) {
  __shared__ unsigned short lds[64][72];
  int bid = blockIdx.x;
  int t = threadIdx.x;
  int ct = bid & 3;
  int pt = (bid >> 2) & 255;
  int b  = bid >> 10;
  const float* src = x + ((size_t)(b * HW_ + pt * 64)) * C_ + ct * 64;
#pragma unroll
  for (int e = 0; e < 4; e++) {
    int lin = t + e * 256;          // (p, c4)
    int p = lin >> 4, c4 = lin & 15;
    float4 v = *(const float4*)(src + (size_t)p * C_ + c4 * 4);
    ushort4 h;
    h.x = f2bf(v.x); h.y = f2bf(v.y); h.z = f2bf(v.z); h.w = f2bf(v.w);
    *(ushort4*)(xb + ((size_t)(b * HW_ + pt * 64 + p)) * C_ + ct * 64 + c4 * 4) = h;
    lds[c4 * 4 + 0][p] = h.x;
    lds[c4 * 4 + 1][p] = h.y;
    lds[c4 * 4 + 2][p] = h.z;
    lds[c4 * 4 + 3][p] = h.w;
  }
  __syncthreads();
#pragma unroll
  for (int e = 0; e < 4; e++) {
    int lin = t + e * 256;          // (c, p4)
    int c = lin >> 4, p4 = lin & 15;
    ushort4 h;
    h.x = lds[c][p4 * 4 + 0];
    h.y = lds[c][p4 * 4 + 1];
    h.z = lds[c][p4 * 4 + 2];
    h.w = lds[c][p4 * 4 + 3];
    *(ushort4*)(xT + ((size_t)(b * C_ + ct * 64 + c)) * HW_ + pt * 64 + p4 * 4) = h;
  }
}

// ---------------------------------------------------------------------------
// K2: S partials, exploiting symmetry. grid 128 = b(4)*ks(32), 512 thr.
// Each block: FULL 256x256 output over its K-chunk of 512, staged as 4 phases
// of BK=128 into ONE 64 KiB LDS panel (256 rows x 128 k). Both MFMA operands
// are fragments of the same panel -> each xT element is read from HBM exactly
// once. Rows are 16 octets (16B units), xor-swizzled: slot s of row r holds
// global octet s ^ (r&15) -> both the linear global_load_lds scatter and the
// ds_read_b128 fragment reads stay at free 2-way bank aliasing.
// Wave w: quadrant q=w>>1 (wm=q>>1, wn=q&1), half h=w&1 -> 64x128 sub-tile.
// K order identical to R3 (k ascending in steps of 32) -> bitwise-same S.
// ---------------------------------------------------------------------------
__global__ __launch_bounds__(512) void k_sgemm(const unsigned short* __restrict__ xT,
                                               float* __restrict__ part) {
  __shared__ unsigned short Pt[256 * 128];   // 64 KiB
  int bid = blockIdx.x;
  int ks = bid & 31, b = bid >> 5;
  const unsigned short* Pb = xT + ((size_t)b * C_) * HW_ + ks * 512;
  int t = threadIdx.x, lane = t & 63, w = t >> 6;   // 8 waves
  int wq = w >> 1, h = w & 1;
  int wm = wq >> 1, wn = wq & 1;
  int l15 = lane & 15, l4 = lane >> 4;
  floatx4 acc[4][8];
  floatx4 z = {0.f, 0.f, 0.f, 0.f};
#pragma unroll
  for (int i = 0; i < 4; i++)
#pragma unroll
    for (int j = 0; j < 8; j++) acc[i][j] = z;

  for (int ph = 0; ph < 4; ph++) {
    if (ph) __syncthreads();               // protect LDS reuse
    // stage 256 rows x 128 k: 64 issues (1 KiB each), 8 per wave
#pragma unroll
    for (int i = 0; i < 8; i++) {
      int issue = w * 8 + i;               // 0..63
      int row = issue * 4 + l4;            // 0..255
      int goct = l15 ^ (row & 15);
      gl_lds16(Pb + (size_t)row * HW_ + ph * 128 + goct * 8, Pt + issue * 512);
    }
    __syncthreads();                       // drains vmcnt(0)
#pragma unroll
    for (int kk = 0; kk < 4; kk++) {       // 4 k-steps of 32 per phase
      short8 af[4], bfv[8];
      int oct = kk * 4 + l4;
#pragma unroll
      for (int tm = 0; tm < 4; tm++) {
        int row = wm * 128 + h * 64 + tm * 16 + l15;
        af[tm] = *(const short8*)(Pt + row * 128 + ((oct ^ (row & 15)) * 8));
      }
#pragma unroll
      for (int tn = 0; tn < 8; tn++) {
        int row = wn * 128 + tn * 16 + l15;
        bfv[tn] = *(const short8*)(Pt + row * 128 + ((oct ^ (row & 15)) * 8));
      }
#pragma unroll
      for (int tm = 0; tm < 4; tm++)
#pragma unroll
        for (int tn = 0; tn < 8; tn++)
          acc[tm][tn] = __builtin_amdgcn_mfma_f32_16x16x32_bf16(af[tm], bfv[tn],
                                                                acc[tm][tn], 0, 0, 0);
    }
  }
  // epilogue: streaming fp32 partial tile [b][ks][256][256]
  float* pb = part + (size_t)(b * 32 + ks) * 65536;
#pragma unroll
  for (int tm = 0; tm < 4; tm++)
#pragma unroll
    for (int tn = 0; tn < 8; tn++)
#pragma unroll
      for (int r = 0; r < 4; r++) {
        int m = wm * 128 + h * 64 + tm * 16 + l4 * 4 + r;  // C/D: row=(lane>>4)*4+reg
        int n = wn * 128 + tn * 16 + l15;                  //      col=lane&15
        pb[m * 256 + n] = acc[tm][tn][r];
      }
}

// K2r: reduce 32 K-partials -> S fp32 [b][256][256]. grid 1024 x 256.
__global__ __launch_bounds__(256) void k_sred(const float* __restrict__ part,
                                              float* __restrict__ S) {
  int idx = blockIdx.x * 256 + threadIdx.x;   // 0..262143
  int b = idx >> 16;
  int mn = idx & 65535;
  const float* p = part + ((size_t)b << 21) + mn;
  float s = 0.f;
#pragma unroll
  for (int k = 0; k < 32; k++) s += p[(size_t)k << 16];
  S[idx] = s;
}

// ---------------------------------------------------------------------------
// K3a: SWq = S@Wq, SWk = S@Wk (fp32, 64x64 tiles). grid 128 = b(4)*mt(4)*nt(8).
// R4: A staged transposed [k][m] (pad 68 keeps float4 alignment, 2-way banks)
// so the inner loop is 2x ds_read_b128 per k instead of 8x ds_read_b32.
// ---------------------------------------------------------------------------
__global__ __launch_bounds__(256) void k_gemm_sw(const float* __restrict__ S,
                                                 const float* __restrict__ Wq,
                                                 const float* __restrict__ Wk,
                                                 float* __restrict__ SWq,
                                                 float* __restrict__ SWk) {
  __shared__ float Ast[16][68];
  __shared__ float Bs[16][68];
  int bid = blockIdx.x;
  int nt = bid & 7, mt = (bid >> 3) & 3, b = bid >> 5;
  int mb = mt * 64;
  const float* Wsel = (nt < 4) ? Wq : Wk;
  int nb = (nt & 3) * 64;
  int t = threadIdx.x, tx = t & 15, ty = t >> 4;
  float acc[4][4] = {};
  for (int kt = 0; kt < 16; kt++) {
    {
      int row = t >> 2, kq = t & 3;
      float4 v = *(const float4*)(S + ((size_t)(b * C_ + mb + row)) * C_ + kt * 16 + kq * 4);
      Ast[kq * 4 + 0][row] = v.x; Ast[kq * 4 + 1][row] = v.y;
      Ast[kq * 4 + 2][row] = v.z; Ast[kq * 4 + 3][row] = v.w;
    }
    {
      int kk = t >> 4, n4 = t & 15;
      float4 v = *(const float4*)(Wsel + ((size_t)(kt * 16 + kk)) * C_ + nb + n4 * 4);
      *(float4*)&Bs[kk][n4 * 4] = v;
    }
    __syncthreads();
#pragma unroll
    for (int k = 0; k < 16; k++) {
      float4 a4 = *(const float4*)&Ast[k][ty * 4];
      float4 b4 = *(const float4*)&Bs[k][tx * 4];
      float a[4] = {a4.x, a4.y, a4.z, a4.w};
      float bb[4] = {b4.x, b4.y, b4.z, b4.w};
#pragma unroll
      for (int i = 0; i < 4; i++)
#pragma unroll
        for (int j = 0; j < 4; j++) acc[i][j] += a[i] * bb[j];
    }
    __syncthreads();
  }
#pragma unroll
  for (int i = 0; i < 4; i++)
#pragma unroll
    for (int j = 0; j < 4; j++) {
      int row = mb + ty * 4 + i;
      int ng = nt * 64 + tx * 4 + j;
      if (ng < 256) SWq[((size_t)(b * C_ + row)) * C_ + ng] = acc[i][j];
      else          SWk[((size_t)(b * C_ + row)) * C_ + ng - 256] = acc[i][j];
    }
}

// ---------------------------------------------------------------------------
// K3f: fused G_h + norms + softmax + U_h. grid 32 = (b,h), 256 thr.
// ---------------------------------------------------------------------------
__global__ __launch_bounds__(256) void k_fuse(const float* __restrict__ Wq,
                                              const float* __restrict__ Wk,
                                              const float* __restrict__ SWq,
                                              const float* __restrict__ SWk,
                                              const float* __restrict__ Wout,
                                              float* __restrict__ U) {
  __shared__ float Wqh[256][32];    // 32 KiB (reused as Wo[32][256] for U phase)
  __shared__ float Wkh[256][32];
  __shared__ float SWqh[256][32];
  __shared__ float SWkh[256][32];   // total 128 KiB
  __shared__ float Lg[32][33];
  __shared__ float qp[8][32], kp[8][32], qin[32], kin[32];
  int b = blockIdx.x >> 3, h = blockIdx.x & 7;
  int t = threadIdx.x;
  int col = t & 31, rgrp = t >> 5;               // 8 rows per sweep
  for (int r0 = 0; r0 < 256; r0 += 8) {
    int row = r0 + rgrp;
    Wqh[row][col]  = Wq[(size_t)row * C_ + h * 32 + col];
    Wkh[row][col]  = Wk[(size_t)row * C_ + h * 32 + col];
    SWqh[row][col] = SWq[((size_t)(b * C_ + row)) * C_ + h * 32 + col];
    SWkh[row][col] = SWk[((size_t)(b * C_ + row)) * C_ + h * 32 + col];
  }
  __syncthreads();
  {
    float g[4] = {0.f, 0.f, 0.f, 0.f};
    for (int k = 0; k < 256; k++) {
      float swk = SWkh[k][col];
#pragma unroll
      for (int r = 0; r < 4; r++) g[r] += Wqh[k][rgrp + 8 * r] * swk;
    }
#pragma unroll
    for (int r = 0; r < 4; r++) Lg[rgrp + 8 * r][col] = g[r];
  }
  {
    float sq = 0.f, sk = 0.f;
    for (int k = rgrp * 32; k < rgrp * 32 + 32; k++) {
      sq += Wqh[k][col] * SWqh[k][col];
      sk += Wkh[k][col] * SWkh[k][col];
    }
    qp[rgrp][col] = sq;
    kp[rgrp][col] = sk;
  }
  __syncthreads();
  if (t < 32) {
    float a = 0.f;
#pragma unroll
    for (int p = 0; p < 8; p++) a += qp[p][t];
    qin[t] = rsqrtf(a);
  } else if (t < 64) {
    int j = t - 32;
    float a = 0.f;
#pragma unroll
    for (int p = 0; p < 8; p++) a += kp[p][j];
    kin[j] = rsqrtf(a);
  }
  __syncthreads();
  if (t < 32) {
    float row[32];
    float mx = -1e30f;
#pragma unroll
    for (int j = 0; j < 32; j++) {
      row[j] = Lg[t][j] * qin[t] * kin[j] * 0.0078125f;   // /sqrt(16384)
      mx = fmaxf(mx, row[j]);
    }
    float sum = 0.f;
#pragma unroll
    for (int j = 0; j < 32; j++) { row[j] = __expf(row[j] - mx); sum += row[j]; }
    float inv = 1.0f / sum;
#pragma unroll
    for (int j = 0; j < 32; j++) Lg[t][j] = row[j] * inv;
  }
  __syncthreads();
  float (*Wo)[256] = reinterpret_cast<float(*)[256]>(&Wqh[0][0]);
#pragma unroll
  for (int r = 0; r < 32; r++) Wo[r][t] = Wout[((size_t)(h * 32 + r)) * C_ + t];
  __syncthreads();
  for (int j = 0; j < 32; j++) {
    float a = 0.f;
#pragma unroll
    for (int i2 = 0; i2 < 32; i2++) a += Lg[i2][j] * Wo[i2][t];
    U[((size_t)(b * C_ + h * 32 + j)) * C_ + t] = a;
  }
}

// ---------------------------------------------------------------------------
// K3e: W3 = Wv @ U[b], emitted transposed bf16: W3bT[b][n][c]. grid 64.
// R4: same [k][m] LDS treatment as K3a.
// ---------------------------------------------------------------------------
__global__ __launch_bounds__(256) void k_gemm_w3(const float* __restrict__ Wv,
                                                 const float* __restrict__ U,
                                                 unsigned short* __restrict__ W3bT) {
  __shared__ float Ast[16][68];
  __shared__ float Bs[16][68];
  int bid = blockIdx.x;
  int nt = bid & 3, mt = (bid >> 2) & 3, b = bid >> 4;
  int mb = mt * 64, nb = nt * 64;
  int t = threadIdx.x, tx = t & 15, ty = t >> 4;
  float acc[4][4] = {};
  for (int kt = 0; kt < 16; kt++) {
    {
      int row = t >> 2, kq = t & 3;
      float4 v = *(const float4*)(Wv + ((size_t)(mb + row)) * C_ + kt * 16 + kq * 4);
      Ast[kq * 4 + 0][row] = v.x; Ast[kq * 4 + 1][row] = v.y;
      Ast[kq * 4 + 2][row] = v.z; Ast[kq * 4 + 3][row] = v.w;
    }
    {
      int kk = t >> 4, n4 = t & 15;
      float4 v = *(const float4*)(U + ((size_t)(b * C_ + kt * 16 + kk)) * C_ + nb + n4 * 4);
      *(float4*)&Bs[kk][n4 * 4] = v;
    }
    __syncthreads();
#pragma unroll
    for (int k = 0; k < 16; k++) {
      float4 a4 = *(const float4*)&Ast[k][ty * 4];
      float4 b4 = *(const float4*)&Bs[k][tx * 4];
      float a[4] = {a4.x, a4.y, a4.z, a4.w};
      float bb[4] = {b4.x, b4.y, b4.z, b4.w};
#pragma unroll
      for (int i = 0; i < 4; i++)
#pragma unroll
        for (int j = 0; j < 4; j++) acc[i][j] += a[i] * bb[j];
    }
    __syncthreads();
  }
#pragma unroll
  for (int i = 0; i < 4; i++)
#pragma unroll
    for (int j = 0; j < 4; j++)
      W3bT[((size_t)(b * C_ + nb + tx * 4 + j)) * C_ + mb + ty * 4 + i] = f2bf(acc[i][j]);
}

// ---------------------------------------------------------------------------
// K4: out = xb @ W3[b], fp32 out. grid 512 = mtile. BN=256 (full width per
// block) so each xb row is staged exactly once. BK=64, 4 stages, swizzled
// glds path (8-slot rows). Wave w: row-half h=w>>1, col-half c2=w&1.
// ---------------------------------------------------------------------------
__global__ __launch_bounds__(256) void k_out(const unsigned short* __restrict__ xb,
                                             const unsigned short* __restrict__ W3bT,
                                             float* __restrict__ out) {
  __shared__ unsigned short At[128 * 64];   // 16 KiB
  __shared__ unsigned short Bt[256 * 64];   // 32 KiB
  int mtile = blockIdx.x;
  int b = mtile >> 7;
  const unsigned short* Ab = xb + (size_t)mtile * 128 * C_;
  const unsigned short* Bb = W3bT + (size_t)b * C_ * C_;
  int t = threadIdx.x, lane = t & 63, w = t >> 6;
  int h = w >> 1, c2 = w & 1;
  int l8 = lane >> 3, l7 = lane & 7;
  int srcoct = l7 ^ l8;
  int l15 = lane & 15, l4 = lane >> 4;
  floatx4 acc[4][8];
  floatx4 z = {0.f, 0.f, 0.f, 0.f};
#pragma unroll
  for (int i = 0; i < 4; i++)
#pragma unroll
    for (int j = 0; j < 8; j++) acc[i][j] = z;
  for (int s = 0; s < 4; s++) {
    if (s) __syncthreads();
#pragma unroll
    for (int i = 0; i < 4; i++) {
      int ia = w * 4 + i;                  // 0..15 -> A rows 0..127
      int row = ia * 8 + l8;
      gl_lds16(Ab + (size_t)row * C_ + s * 64 + srcoct * 8, At + ia * 512);
    }
#pragma unroll
    for (int i = 0; i < 8; i++) {
      int ib = w * 8 + i;                  // 0..31 -> B rows 0..255
      int row = ib * 8 + l8;
      gl_lds16(Bb + (size_t)row * C_ + s * 64 + srcoct * 8, Bt + ib * 512);
    }
    __syncthreads();
#pragma unroll
    for (int kk = 0; kk < 2; kk++) {
      short8 af[4], bfv[8];
      int oct = kk * 4 + l4;
#pragma unroll
      for (int tm = 0; tm < 4; tm++) {
        int row = h * 64 + tm * 16 + l15;
        af[tm] = *(const short8*)(At + row * 64 + ((oct ^ (row & 7)) * 8));
      }
#pragma unroll
      for (int tn = 0; tn < 8; tn++) {
        int row = c2 * 128 + tn * 16 + l15;
        bfv[tn] = *(const short8*)(Bt + row * 64 + ((oct ^ (row & 7)) * 8));
      }
#pragma unroll
      for (int tm = 0; tm < 4; tm++)
#pragma unroll
        for (int tn = 0; tn < 8; tn++)
          acc[tm][tn] = __builtin_amdgcn_mfma_f32_16x16x32_bf16(af[tm], bfv[tn],
                                                                acc[tm][tn], 0, 0, 0);
    }
  }
  float* ob = out + (size_t)mtile * 128 * C_;
#pragma unroll
  for (int tm = 0; tm < 4; tm++)
#pragma unroll
    for (int tn = 0; tn < 8; tn++)
#pragma unroll
      for (int r = 0; r < 4; r++) {
        int m = h * 64 + tm * 16 + l4 * 4 + r;
        int n = c2 * 128 + tn * 16 + l15;
        ob[(size_t)m * C_ + n] = acc[tm][tn][r];
      }
}

// ---------------------------------------------------------------------------
extern "C" void kernel_launch(void* const* d_in, const int* in_sizes, int n_in,
                              void* d_out, int out_size, void* d_ws, size_t ws_size,
                              hipStream_t stream) {
  const float* x    = (const float*)d_in[0];
  const float* Wq   = (const float*)d_in[1];
  const float* Wk   = (const float*)d_in[2];
  const float* Wv   = (const float*)d_in[3];
  const float* Wout = (const float*)d_in[4];
  float* out = (float*)d_out;

  // workspace carve-up (~100.5 MiB)
  unsigned short* xT = (unsigned short*)d_ws;          // 4*256*16384 bf16 = 32 MiB
  unsigned short* xb = xT + (size_t)16777216;          // 32 MiB
  float* part = (float*)(xb + (size_t)16777216);       // 4*32*256*256 fp32 = 32 MiB
  float* S    = part + (size_t)8388608;                // 1 MiB
  float* SWq  = S + 262144;                            // 1 MiB
  float* SWk  = SWq + 262144;                          // 1 MiB
  float* U    = SWk + 262144;                          // 1 MiB
  unsigned short* W3bT = (unsigned short*)(U + 262144); // 512 KiB

  k_cast_tr<<<dim3(4096), dim3(256), 0, stream>>>(x, xb, xT);
  k_sgemm<<<dim3(128), dim3(512), 0, stream>>>(xT, part);
  k_sred<<<dim3(1024), dim3(256), 0, stream>>>(part, S);
  k_gemm_sw<<<dim3(128), dim3(256), 0, stream>>>(S, Wq, Wk, SWq, SWk);
  k_fuse<<<dim3(32), dim3(256), 0, stream>>>(Wq, Wk, SWq, SWk, Wout, U);
  k_gemm_w3<<<dim3(64), dim3(256), 0, stream>>>(Wv, U, W3bT);
  k_out<<<dim3(512), dim3(256), 0, stream>>>(xb, W3bT, out);
}

// Round 2
// 218.940 us; speedup vs baseline: 1.0597x; 1.0597x over previous
//
#include <hip/hip_runtime.h>

// SpectralMultiHeadAttention on MI355X (gfx950)
// b=4, hw=16384, c=256, heads=8, dh=32.
// Reformulation: S[b] = x^T x (256x256);  G = Wq^T S Wk;  qss = diag(Wq^T S Wq);
// kss = diag(Wk^T S Wk);  A = softmax(G_blocks / (nq nk sqrt(hw)));
// out = x @ (Wv @ Abig^T @ Wout).   q/k/v never materialized.
// R5: k_cast_tr DELETED (chain was latency-bound, not BW-bound: R4's -130MB
//     traffic cut moved dur_us by 0.1%). k_sgemm reads fp32 x directly and
//     does cast+transpose into its LDS panel (ds_write_b32 pairs, 2-way
//     banks, same XOR swizzle -> bitwise-same S). k_out reads A-fragments
//     directly from fp32 x (L3-hot) with register f2bf; B stays on the
//     global_load_lds path. 6 kernels instead of 7, -134 MB materialization.

#define B_   4
#define HW_  16384
#define C_   256

typedef __attribute__((ext_vector_type(8))) short short8;
typedef __attribute__((ext_vector_type(4))) float floatx4;

__device__ __forceinline__ unsigned short f2bf(float f) {
  unsigned u = __builtin_bit_cast(unsigned, f);
  u += 0x7FFFu + ((u >> 16) & 1u);          // round-to-nearest-even
  return (unsigned short)(u >> 16);
}

__device__ __forceinline__ void gl_lds16(const unsigned short* g, unsigned short* l) {
  __builtin_amdgcn_global_load_lds(
      (const __attribute__((address_space(1))) unsigned int*)g,
      (__attribute__((address_space(3))) unsigned int*)l, 16, 0, 0);
}

// ---------------------------------------------------------------------------
// K2: S partials, exploiting symmetry. grid 128 = b(4)*ks(32), 512 thr.
// Each block: FULL 256x256 output over its K-chunk of 512 hw, staged as 4
// phases of BK=128 from fp32 x with in-kernel cast+transpose into ONE 64 KiB
// LDS panel Pt[256 c][128 hw] bf16. Rows are 16 octets (16B units),
// xor-swizzled: global octet o of row r sits at slot o ^ (r&15).
// Staging: task (cq 0..63, hp 0..63): load float4 at rows hw=2hp,2hp+1,
// pack bf16 pairs, 4x ds_write_b32 -> 32 banks at 2-way (free).
// K order identical to R4 -> bitwise-same S.
// ---------------------------------------------------------------------------
__global__ __launch_bounds__(512) void k_sgemm(const float* __restrict__ x,
                                               float* __restrict__ part) {
  __shared__ unsigned short Pt[256 * 128];   // 64 KiB
  int bid = blockIdx.x;
  int ks = bid & 31, b = bid >> 5;
  const float* xv = x + ((size_t)(b * HW_ + ks * 512)) * C_;
  int t = threadIdx.x, lane = t & 63, w = t >> 6;   // 8 waves
  int wq = w >> 1, hh = w & 1;
  int wm = wq >> 1, wn = wq & 1;
  int l15 = lane & 15, l4 = lane >> 4;
  int s_cq  = (lane >> 3) | (w << 3);       // 0..63: which c-quad
  int s_hpl = lane & 7;                     // low 3 bits of hw-pair
  floatx4 acc[4][8];
  floatx4 z = {0.f, 0.f, 0.f, 0.f};
#pragma unroll
  for (int i = 0; i < 4; i++)
#pragma unroll
    for (int j = 0; j < 8; j++) acc[i][j] = z;

  for (int ph = 0; ph < 4; ph++) {
    if (ph) __syncthreads();               // protect LDS reuse
#pragma unroll
    for (int e = 0; e < 8; e++) {
      int hp = s_hpl | (e << 3);           // 0..63
      int hw = hp * 2;
      const float* src = xv + ((size_t)(ph * 128 + hw)) * C_ + s_cq * 4;
      float4 v0 = *(const float4*)src;
      float4 v1 = *(const float4*)(src + C_);
      float a0[4] = {v0.x, v0.y, v0.z, v0.w};
      float a1[4] = {v1.x, v1.y, v1.z, v1.w};
#pragma unroll
      for (int i = 0; i < 4; i++) {
        unsigned u = (unsigned)f2bf(a0[i]) | ((unsigned)f2bf(a1[i]) << 16);
        int r = s_cq * 4 + i;
        int slot = (hp >> 2) ^ (r & 15);
        ((unsigned*)Pt)[r * 64 + slot * 4 + (hp & 3)] = u;
      }
    }
    __syncthreads();
#pragma unroll
    for (int kk = 0; kk < 4; kk++) {       // 4 k-steps of 32 per phase
      short8 af[4], bfv[8];
      int oct = kk * 4 + l4;
#pragma unroll
      for (int tm = 0; tm < 4; tm++) {
        int row = wm * 128 + hh * 64 + tm * 16 + l15;
        af[tm] = *(const short8*)(Pt + row * 128 + ((oct ^ (row & 15)) * 8));
      }
#pragma unroll
      for (int tn = 0; tn < 8; tn++) {
        int row = wn * 128 + tn * 16 + l15;
        bfv[tn] = *(const short8*)(Pt + row * 128 + ((oct ^ (row & 15)) * 8));
      }
#pragma unroll
      for (int tm = 0; tm < 4; tm++)
#pragma unroll
        for (int tn = 0; tn < 8; tn++)
          acc[tm][tn] = __builtin_amdgcn_mfma_f32_16x16x32_bf16(af[tm], bfv[tn],
                                                                acc[tm][tn], 0, 0, 0);
    }
  }
  // epilogue: streaming fp32 partial tile [b][ks][256][256]
  float* pb = part + (size_t)(b * 32 + ks) * 65536;
#pragma unroll
  for (int tm = 0; tm < 4; tm++)
#pragma unroll
    for (int tn = 0; tn < 8; tn++)
#pragma unroll
      for (int r = 0; r < 4; r++) {
        int m = wm * 128 + hh * 64 + tm * 16 + l4 * 4 + r;  // C/D: row=(lane>>4)*4+reg
        int n = wn * 128 + tn * 16 + l15;                   //      col=lane&15
        pb[m * 256 + n] = acc[tm][tn][r];
      }
}

// K2r: reduce 32 K-partials -> S fp32 [b][256][256]. grid 1024 x 256.
__global__ __launch_bounds__(256) void k_sred(const float* __restrict__ part,
                                              float* __restrict__ S) {
  int idx = blockIdx.x * 256 + threadIdx.x;   // 0..262143
  int b = idx >> 16;
  int mn = idx & 65535;
  const float* p = part + ((size_t)b << 21) + mn;
  float s = 0.f;
#pragma unroll
  for (int k = 0; k < 32; k++) s += p[(size_t)k << 16];
  S[idx] = s;
}

// ---------------------------------------------------------------------------
// K3a: SWq = S@Wq, SWk = S@Wk (fp32, 64x64 tiles). grid 128 = b(4)*mt(4)*nt(8).
// A staged transposed [k][m] (pad 68 keeps float4 alignment, 2-way banks)
// so the inner loop is 2x ds_read_b128 per k instead of 8x ds_read_b32.
// ---------------------------------------------------------------------------
__global__ __launch_bounds__(256) void k_gemm_sw(const float* __restrict__ S,
                                                 const float* __restrict__ Wq,
                                                 const float* __restrict__ Wk,
                                                 float* __restrict__ SWq,
                                                 float* __restrict__ SWk) {
  __shared__ float Ast[16][68];
  __shared__ float Bs[16][68];
  int bid = blockIdx.x;
  int nt = bid & 7, mt = (bid >> 3) & 3, b = bid >> 5;
  int mb = mt * 64;
  const float* Wsel = (nt < 4) ? Wq : Wk;
  int nb = (nt & 3) * 64;
  int t = threadIdx.x, tx = t & 15, ty = t >> 4;
  float acc[4][4] = {};
  for (int kt = 0; kt < 16; kt++) {
    {
      int row = t >> 2, kq = t & 3;
      float4 v = *(const float4*)(S + ((size_t)(b * C_ + mb + row)) * C_ + kt * 16 + kq * 4);
      Ast[kq * 4 + 0][row] = v.x; Ast[kq * 4 + 1][row] = v.y;
      Ast[kq * 4 + 2][row] = v.z; Ast[kq * 4 + 3][row] = v.w;
    }
    {
      int kk = t >> 4, n4 = t & 15;
      float4 v = *(const float4*)(Wsel + ((size_t)(kt * 16 + kk)) * C_ + nb + n4 * 4);
      *(float4*)&Bs[kk][n4 * 4] = v;
    }
    __syncthreads();
#pragma unroll
    for (int k = 0; k < 16; k++) {
      float4 a4 = *(const float4*)&Ast[k][ty * 4];
      float4 b4 = *(const float4*)&Bs[k][tx * 4];
      float a[4] = {a4.x, a4.y, a4.z, a4.w};
      float bb[4] = {b4.x, b4.y, b4.z, b4.w};
#pragma unroll
      for (int i = 0; i < 4; i++)
#pragma unroll
        for (int j = 0; j < 4; j++) acc[i][j] += a[i] * bb[j];
    }
    __syncthreads();
  }
#pragma unroll
  for (int i = 0; i < 4; i++)
#pragma unroll
    for (int j = 0; j < 4; j++) {
      int row = mb + ty * 4 + i;
      int ng = nt * 64 + tx * 4 + j;
      if (ng < 256) SWq[((size_t)(b * C_ + row)) * C_ + ng] = acc[i][j];
      else          SWk[((size_t)(b * C_ + row)) * C_ + ng - 256] = acc[i][j];
    }
}

// ---------------------------------------------------------------------------
// K3f: fused G_h + norms + softmax + U_h. grid 32 = (b,h), 256 thr.
// ---------------------------------------------------------------------------
__global__ __launch_bounds__(256) void k_fuse(const float* __restrict__ Wq,
                                              const float* __restrict__ Wk,
                                              const float* __restrict__ SWq,
                                              const float* __restrict__ SWk,
                                              const float* __restrict__ Wout,
                                              float* __restrict__ U) {
  __shared__ float Wqh[256][32];    // 32 KiB (reused as Wo[32][256] for U phase)
  __shared__ float Wkh[256][32];
  __shared__ float SWqh[256][32];
  __shared__ float SWkh[256][32];   // total 128 KiB
  __shared__ float Lg[32][33];
  __shared__ float qp[8][32], kp[8][32], qin[32], kin[32];
  int b = blockIdx.x >> 3, h = blockIdx.x & 7;
  int t = threadIdx.x;
  int col = t & 31, rgrp = t >> 5;               // 8 rows per sweep
  for (int r0 = 0; r0 < 256; r0 += 8) {
    int row = r0 + rgrp;
    Wqh[row][col]  = Wq[(size_t)row * C_ + h * 32 + col];
    Wkh[row][col]  = Wk[(size_t)row * C_ + h * 32 + col];
    SWqh[row][col] = SWq[((size_t)(b * C_ + row)) * C_ + h * 32 + col];
    SWkh[row][col] = SWk[((size_t)(b * C_ + row)) * C_ + h * 32 + col];
  }
  __syncthreads();
  {
    float g[4] = {0.f, 0.f, 0.f, 0.f};
    for (int k = 0; k < 256; k++) {
      float swk = SWkh[k][col];
#pragma unroll
      for (int r = 0; r < 4; r++) g[r] += Wqh[k][rgrp + 8 * r] * swk;
    }
#pragma unroll
    for (int r = 0; r < 4; r++) Lg[rgrp + 8 * r][col] = g[r];
  }
  {
    float sq = 0.f, sk = 0.f;
    for (int k = rgrp * 32; k < rgrp * 32 + 32; k++) {
      sq += Wqh[k][col] * SWqh[k][col];
      sk += Wkh[k][col] * SWkh[k][col];
    }
    qp[rgrp][col] = sq;
    kp[rgrp][col] = sk;
  }
  __syncthreads();
  if (t < 32) {
    float a = 0.f;
#pragma unroll
    for (int p = 0; p < 8; p++) a += qp[p][t];
    qin[t] = rsqrtf(a);
  } else if (t < 64) {
    int j = t - 32;
    float a = 0.f;
#pragma unroll
    for (int p = 0; p < 8; p++) a += kp[p][j];
    kin[j] = rsqrtf(a);
  }
  __syncthreads();
  if (t < 32) {
    float row[32];
    float mx = -1e30f;
#pragma unroll
    for (int j = 0; j < 32; j++) {
      row[j] = Lg[t][j] * qin[t] * kin[j] * 0.0078125f;   // /sqrt(16384)
      mx = fmaxf(mx, row[j]);
    }
    float sum = 0.f;
#pragma unroll
    for (int j = 0; j < 32; j++) { row[j] = __expf(row[j] - mx); sum += row[j]; }
    float inv = 1.0f / sum;
#pragma unroll
    for (int j = 0; j < 32; j++) Lg[t][j] = row[j] * inv;
  }
  __syncthreads();
  float (*Wo)[256] = reinterpret_cast<float(*)[256]>(&Wqh[0][0]);
#pragma unroll
  for (int r = 0; r < 32; r++) Wo[r][t] = Wout[((size_t)(h * 32 + r)) * C_ + t];
  __syncthreads();
  for (int j = 0; j < 32; j++) {
    float a = 0.f;
#pragma unroll
    for (int i2 = 0; i2 < 32; i2++) a += Lg[i2][j] * Wo[i2][t];
    U[((size_t)(b * C_ + h * 32 + j)) * C_ + t] = a;
  }
}

// ---------------------------------------------------------------------------
// K3e: W3 = Wv @ U[b], emitted transposed bf16: W3bT[b][n][c]. grid 64.
// ---------------------------------------------------------------------------
__global__ __launch_bounds__(256) void k_gemm_w3(const float* __restrict__ Wv,
                                                 const float* __restrict__ U,
                                                 unsigned short* __restrict__ W3bT) {
  __shared__ float Ast[16][68];
  __shared__ float Bs[16][68];
  int bid = blockIdx.x;
  int nt = bid & 3, mt = (bid >> 2) & 3, b = bid >> 4;
  int mb = mt * 64, nb = nt * 64;
  int t = threadIdx.x, tx = t & 15, ty = t >> 4;
  float acc[4][4] = {};
  for (int kt = 0; kt < 16; kt++) {
    {
      int row = t >> 2, kq = t & 3;
      float4 v = *(const float4*)(Wv + ((size_t)(mb + row)) * C_ + kt * 16 + kq * 4);
      Ast[kq * 4 + 0][row] = v.x; Ast[kq * 4 + 1][row] = v.y;
      Ast[kq * 4 + 2][row] = v.z; Ast[kq * 4 + 3][row] = v.w;
    }
    {
      int kk = t >> 4, n4 = t & 15;
      float4 v = *(const float4*)(U + ((size_t)(b * C_ + kt * 16 + kk)) * C_ + nb + n4 * 4);
      *(float4*)&Bs[kk][n4 * 4] = v;
    }
    __syncthreads();
#pragma unroll
    for (int k = 0; k < 16; k++) {
      float4 a4 = *(const float4*)&Ast[k][ty * 4];
      float4 b4 = *(const float4*)&Bs[k][tx * 4];
      float a[4] = {a4.x, a4.y, a4.z, a4.w};
      float bb[4] = {b4.x, b4.y, b4.z, b4.w};
#pragma unroll
      for (int i = 0; i < 4; i++)
#pragma unroll
        for (int j = 0; j < 4; j++) acc[i][j] += a[i] * bb[j];
    }
    __syncthreads();
  }
#pragma unroll
  for (int i = 0; i < 4; i++)
#pragma unroll
    for (int j = 0; j < 4; j++)
      W3bT[((size_t)(b * C_ + nb + tx * 4 + j)) * C_ + mb + ty * 4 + i] = f2bf(acc[i][j]);
}

// ---------------------------------------------------------------------------
// K4: out = x @ W3[b], fp32 out. grid 512 = mtile. BN=256 per block.
// A-fragments read DIRECTLY from fp32 x (L3-hot) + register f2bf; B staged
// via swizzled global_load_lds (8-slot rows). BK=64, 4 stages.
// Wave w: row-half hf=w>>1, col-half c2=w&1.
// ---------------------------------------------------------------------------
__global__ __launch_bounds__(256) void k_out(const float* __restrict__ x,
                                             const unsigned short* __restrict__ W3bT,
                                             float* __restrict__ out) {
  __shared__ unsigned short Bt[256 * 64];   // 32 KiB
  int mtile = blockIdx.x;
  int b = mtile >> 7;
  const float* Ax = x + (size_t)mtile * 128 * C_;
  const unsigned short* Bb = W3bT + (size_t)b * C_ * C_;
  int t = threadIdx.x, lane = t & 63, w = t >> 6;
  int hf = w >> 1, c2 = w & 1;
  int l8 = lane >> 3, l7 = lane & 7;
  int srcoct = l7 ^ l8;
  int l15 = lane & 15, l4 = lane >> 4;
  floatx4 acc[4][8];
  floatx4 z = {0.f, 0.f, 0.f, 0.f};
#pragma unroll
  for (int i = 0; i < 4; i++)
#pragma unroll
    for (int j = 0; j < 8; j++) acc[i][j] = z;
  for (int s = 0; s < 4; s++) {
    if (s) __syncthreads();
#pragma unroll
    for (int i = 0; i < 8; i++) {
      int ib = w * 8 + i;                  // 0..31 -> B rows 0..255
      int row = ib * 8 + l8;
      gl_lds16(Bb + (size_t)row * C_ + s * 64 + srcoct * 8, Bt + ib * 512);
    }
    __syncthreads();
#pragma unroll
    for (int kk = 0; kk < 2; kk++) {
      short8 af[4], bfv[8];
      int oct = kk * 4 + l4;
#pragma unroll
      for (int tm = 0; tm < 4; tm++) {
        int row = hf * 64 + tm * 16 + l15;
        const float* p = Ax + (size_t)row * C_ + s * 64 + oct * 8;
        float4 u0 = *(const float4*)p;
        float4 u1 = *(const float4*)(p + 4);
        short8 v;
        v[0] = (short)f2bf(u0.x); v[1] = (short)f2bf(u0.y);
        v[2] = (short)f2bf(u0.z); v[3] = (short)f2bf(u0.w);
        v[4] = (short)f2bf(u1.x); v[5] = (short)f2bf(u1.y);
        v[6] = (short)f2bf(u1.z); v[7] = (short)f2bf(u1.w);
        af[tm] = v;
      }
#pragma unroll
      for (int tn = 0; tn < 8; tn++) {
        int row = c2 * 128 + tn * 16 + l15;
        bfv[tn] = *(const short8*)(Bt + row * 64 + ((oct ^ (row & 7)) * 8));
      }
#pragma unroll
      for (int tm = 0; tm < 4; tm++)
#pragma unroll
        for (int tn = 0; tn < 8; tn++)
          acc[tm][tn] = __builtin_amdgcn_mfma_f32_16x16x32_bf16(af[tm], bfv[tn],
                                                                acc[tm][tn], 0, 0, 0);
    }
  }
  float* ob = out + (size_t)mtile * 128 * C_;
#pragma unroll
  for (int tm = 0; tm < 4; tm++)
#pragma unroll
    for (int tn = 0; tn < 8; tn++)
#pragma unroll
      for (int r = 0; r < 4; r++) {
        int m = hf * 64 + tm * 16 + l4 * 4 + r;
        int n = c2 * 128 + tn * 16 + l15;
        ob[(size_t)m * C_ + n] = acc[tm][tn][r];
      }
}

// ---------------------------------------------------------------------------
extern "C" void kernel_launch(void* const* d_in, const int* in_sizes, int n_in,
                              void* d_out, int out_size, void* d_ws, size_t ws_size,
                              hipStream_t stream) {
  const float* x    = (const float*)d_in[0];
  const float* Wq   = (const float*)d_in[1];
  const float* Wk   = (const float*)d_in[2];
  const float* Wv   = (const float*)d_in[3];
  const float* Wout = (const float*)d_in[4];
  float* out = (float*)d_out;

  // workspace carve-up (~36.5 MiB)
  float* part = (float*)d_ws;                           // 4*32*256*256 fp32 = 32 MiB
  float* S    = part + (size_t)8388608;                 // 1 MiB
  float* SWq  = S + 262144;                             // 1 MiB
  float* SWk  = SWq + 262144;                           // 1 MiB
  float* U    = SWk + 262144;                           // 1 MiB
  unsigned short* W3bT = (unsigned short*)(U + 262144); // 512 KiB

  k_sgemm<<<dim3(128), dim3(512), 0, stream>>>(x, part);
  k_sred<<<dim3(1024), dim3(256), 0, stream>>>(part, S);
  k_gemm_sw<<<dim3(128), dim3(256), 0, stream>>>(S, Wq, Wk, SWq, SWk);
  k_fuse<<<dim3(32), dim3(256), 0, stream>>>(Wq, Wk, SWq, SWk, Wout, U);
  k_gemm_w3<<<dim3(64), dim3(256), 0, stream>>>(Wv, U, W3bT);
  k_out<<<dim3(512), dim3(256), 0, stream>>>(x, W3bT, out);
}